// Round 1
// baseline (607.345 us; speedup 1.0000x reference)
//
#include <hip/hip_runtime.h>
#include <math.h>

#define N_NODES_C 50000
#define N_EDGES_C 800000
#define E_TOT_C   (N_EDGES_C + N_NODES_C)   // 850000 incl. self-loops
#define N_GRAPHS_C 512
#define CH 64

__device__ __forceinline__ float wave_reduce_sum(float v) {
#pragma unroll
    for (int m = 32; m >= 1; m >>= 1) v += __shfl_xor(v, m, 64);
    return v;
}
__device__ __forceinline__ float wave_reduce_max(float v) {
#pragma unroll
    for (int m = 32; m >= 1; m >>= 1) v = fmaxf(v, __shfl_xor(v, m, 64));
    return v;
}

// ---------------- CSR build ----------------

__global__ void hist_kernel(const int* __restrict__ ei, int* __restrict__ deg) {
    int stride = gridDim.x * blockDim.x;
    for (int e = blockIdx.x * blockDim.x + threadIdx.x; e < E_TOT_C; e += stride) {
        int d = (e < N_EDGES_C) ? ei[N_EDGES_C + e] : (e - N_EDGES_C);
        atomicAdd(&deg[d], 1);
    }
}

// single-block exclusive scan over 50000 ints (Hillis-Steele per 1024-chunk)
__global__ void scan_kernel(const int* __restrict__ deg, int* __restrict__ row_ptr) {
    __shared__ int s[1024];
    __shared__ int run;
    int t = threadIdx.x;
    if (t == 0) run = 0;
    __syncthreads();
    for (int base = 0; base < N_NODES_C; base += 1024) {
        int idx = base + t;
        int v = (idx < N_NODES_C) ? deg[idx] : 0;
        s[t] = v;
        __syncthreads();
        for (int off = 1; off < 1024; off <<= 1) {
            int add = (t >= off) ? s[t - off] : 0;
            __syncthreads();
            s[t] += add;
            __syncthreads();
        }
        int incl = s[t];
        int r = run;
        if (idx < N_NODES_C) row_ptr[idx] = r + incl - v;   // exclusive
        int tot = s[1023];
        __syncthreads();
        if (t == 0) run = r + tot;
        __syncthreads();
    }
    if (t == 0) row_ptr[N_NODES_C] = run;   // == E_TOT_C
}

__global__ void scatter_kernel(const int* __restrict__ ei, int* __restrict__ cursor,
                               int* __restrict__ csr_src) {
    int stride = gridDim.x * blockDim.x;
    for (int e = blockIdx.x * blockDim.x + threadIdx.x; e < E_TOT_C; e += stride) {
        int s_, d_;
        if (e < N_EDGES_C) { s_ = ei[e]; d_ = ei[N_EDGES_C + e]; }
        else               { s_ = d_ = e - N_EDGES_C; }
        int pos = atomicAdd(&cursor[d_], 1);
        csr_src[pos] = s_;
    }
}

// ---------------- per-layer kernels ----------------

// h = x @ W  (fused with alpha_src/alpha_dst dot products); wave-per-node
__global__ __launch_bounds__(256) void transform_kernel(
    const float* __restrict__ xin, const float* __restrict__ W,
    const float* __restrict__ a_s, const float* __restrict__ a_d,
    float* __restrict__ hout, float* __restrict__ as_out, float* __restrict__ ad_out)
{
    __shared__ float Wl[64][64];     // [k][c] — lane-consecutive reads, conflict-free
    __shared__ float xs[4][64];
    __shared__ float asv[64], adv[64];
    int t = threadIdx.x;
    for (int i = t; i < 64 * 64; i += 256) Wl[i >> 6][i & 63] = W[i];
    if (t < 64) { asv[t] = a_s[t]; adv[t] = a_d[t]; }
    int w = t >> 6, c = t & 63;
    int n = blockIdx.x * 4 + w;      // 50000 % 4 == 0, no guard needed
    xs[w][c] = xin[n * CH + c];
    __syncthreads();
    float acc = 0.f;
#pragma unroll
    for (int k = 0; k < 64; ++k) acc = fmaf(xs[w][k], Wl[k][c], acc);
    hout[n * CH + c] = acc;
    float vs = wave_reduce_sum(acc * asv[c]);
    float vd = wave_reduce_sum(acc * adv[c]);
    if (c == 0) { as_out[n] = vs; ad_out[n] = vd; }
}

// segment softmax + weighted aggregation + bias + ELU; wave-per-dst-node
__global__ __launch_bounds__(256) void aggregate_kernel(
    const float* __restrict__ h, const float* __restrict__ as,
    const float* __restrict__ ad, const float* __restrict__ bias,
    const int* __restrict__ row_ptr, const int* __restrict__ csr_src,
    float* __restrict__ csr_ex, float* __restrict__ out)
{
    int t = threadIdx.x;
    int w = t >> 6, lane = t & 63;
    int n = blockIdx.x * 4 + w;
    int beg = row_ptr[n], end = row_ptr[n + 1];
    float adn = ad[n];
    // phase 1: segment max (lane-per-edge)
    float m = -1e30f;
    for (int i = beg + lane; i < end; i += 64) {
        float l = as[csr_src[i]] + adn;
        l = (l >= 0.f) ? l : 0.2f * l;
        m = fmaxf(m, l);
    }
    m = wave_reduce_max(m);
    // phase 2: exp + segment sum
    float ssum = 0.f;
    for (int i = beg + lane; i < end; i += 64) {
        float l = as[csr_src[i]] + adn;
        l = (l >= 0.f) ? l : 0.2f * l;
        float ex = expf(l - m);
        csr_ex[i] = ex;
        ssum += ex;
    }
    ssum = wave_reduce_sum(ssum);
    float inv = 1.f / fmaxf(ssum, 1e-16f);
    // phase 3: weighted gather (lane-per-channel, coalesced 256B per edge)
    float acc = 0.f;
    for (int i = beg; i < end; ++i) {
        int s = csr_src[i];          // broadcast load
        float wgt = csr_ex[i] * inv; // broadcast load
        acc = fmaf(wgt, h[s * CH + lane], acc);
    }
    acc += bias[lane];
    out[n * CH + lane] = (acc > 0.f) ? acc : expm1f(acc);
}

// ---------------- pooling ----------------

__global__ __launch_bounds__(256) void pool_kernel(
    const float* __restrict__ h, const int* __restrict__ batch,
    float* __restrict__ out, int* __restrict__ cnt)
{
    int t = threadIdx.x;
    int w = t >> 6, lane = t & 63;
    int n = blockIdx.x * 4 + w;
    int g = batch[n];
    atomicAdd(&out[g * CH + lane], h[n * CH + lane]);
    if (lane == 0) atomicAdd(&cnt[g], 1);
}

__global__ void divide_kernel(float* __restrict__ out, const int* __restrict__ cnt) {
    int i = blockIdx.x * blockDim.x + threadIdx.x;   // 32768 threads
    float c = (float)cnt[i >> 6];
    out[i] /= fmaxf(c, 1.f);
}

// ---------------- launch ----------------

extern "C" void kernel_launch(void* const* d_in, const int* in_sizes, int n_in,
                              void* d_out, int out_size, void* d_ws, size_t ws_size,
                              hipStream_t stream)
{
    const float* x   = (const float*)d_in[0];
    const int*   ei  = (const int*)d_in[1];     // [2, 800000]
    const int*   bat = (const int*)d_in[2];     // [50000]
    const float* W1  = (const float*)d_in[3];
    const float* as1 = (const float*)d_in[4];
    const float* ad1 = (const float*)d_in[5];
    const float* b1  = (const float*)d_in[6];
    const float* W2  = (const float*)d_in[7];
    const float* as2 = (const float*)d_in[8];
    const float* ad2 = (const float*)d_in[9];
    const float* b2  = (const float*)d_in[10];
    float* out = (float*)d_out;

    char* ws = (char*)d_ws;
    size_t off = 0;
    auto alloc = [&](size_t bytes) -> void* {
        void* p = ws + off;
        off += (bytes + 255) & ~size_t(255);
        return p;
    };
    float* hbuf    = (float*)alloc(sizeof(float) * N_NODES_C * CH);
    float* obuf    = (float*)alloc(sizeof(float) * N_NODES_C * CH);
    float* alpha_s = (float*)alloc(sizeof(float) * N_NODES_C);
    float* alpha_d = (float*)alloc(sizeof(float) * N_NODES_C);
    float* csr_ex  = (float*)alloc(sizeof(float) * E_TOT_C);
    int*   deg_cur = (int*)alloc(sizeof(int) * N_NODES_C);
    int*   row_ptr = (int*)alloc(sizeof(int) * (N_NODES_C + 1));
    int*   csr_src = (int*)alloc(sizeof(int) * E_TOT_C);
    int*   cnt     = (int*)alloc(sizeof(int) * N_GRAPHS_C);

    const int NB = N_NODES_C / 4;   // 12500 blocks, 4 nodes (waves) per block

    // CSR build (shared across both layers)
    hipMemsetAsync(deg_cur, 0, sizeof(int) * N_NODES_C, stream);
    hist_kernel<<<1024, 256, 0, stream>>>(ei, deg_cur);
    scan_kernel<<<1, 1024, 0, stream>>>(deg_cur, row_ptr);
    hipMemcpyAsync(deg_cur, row_ptr, sizeof(int) * N_NODES_C,
                   hipMemcpyDeviceToDevice, stream);
    scatter_kernel<<<1024, 256, 0, stream>>>(ei, deg_cur, csr_src);

    // layer 1
    transform_kernel<<<NB, 256, 0, stream>>>(x, W1, as1, ad1, hbuf, alpha_s, alpha_d);
    aggregate_kernel<<<NB, 256, 0, stream>>>(hbuf, alpha_s, alpha_d, b1,
                                             row_ptr, csr_src, csr_ex, obuf);
    // layer 2
    transform_kernel<<<NB, 256, 0, stream>>>(obuf, W2, as2, ad2, hbuf, alpha_s, alpha_d);
    aggregate_kernel<<<NB, 256, 0, stream>>>(hbuf, alpha_s, alpha_d, b2,
                                             row_ptr, csr_src, csr_ex, obuf);

    // global mean pool
    hipMemsetAsync(out, 0, sizeof(float) * N_GRAPHS_C * CH, stream);
    hipMemsetAsync(cnt, 0, sizeof(int) * N_GRAPHS_C, stream);
    pool_kernel<<<NB, 256, 0, stream>>>(obuf, bat, out, cnt);
    divide_kernel<<<128, 256, 0, stream>>>(out, cnt);
}

// Round 2
// 336.380 us; speedup vs baseline: 1.8055x; 1.8055x over previous
//
#include <hip/hip_runtime.h>
#include <math.h>

#define N_NODES_C 50000
#define N_EDGES_C 800000
#define E_TOT_C   (N_EDGES_C + N_NODES_C)   // 850000 incl. self-loops
#define N_GRAPHS_C 512
#define CH 64
#define NBLK_SCAN 196                       // ceil(50000/256)

__device__ __forceinline__ float wave_reduce_sum(float v) {
#pragma unroll
    for (int m = 32; m >= 1; m >>= 1) v += __shfl_xor(v, m, 64);
    return v;
}
__device__ __forceinline__ float wave_reduce_max(float v) {
#pragma unroll
    for (int m = 32; m >= 1; m >>= 1) v = fmaxf(v, __shfl_xor(v, m, 64));
    return v;
}
__device__ __forceinline__ int wave_incl_scan(int v, int lane) {
#pragma unroll
    for (int off = 1; off < 64; off <<= 1) {
        int n = __shfl_up(v, off, 64);
        if (lane >= off) v += n;
    }
    return v;
}

// ---------------- CSR build ----------------

__global__ void hist_kernel(const int* __restrict__ ei, int* __restrict__ deg) {
    int stride = gridDim.x * blockDim.x;
    for (int e = blockIdx.x * blockDim.x + threadIdx.x; e < E_TOT_C; e += stride) {
        int d = (e < N_EDGES_C) ? ei[N_EDGES_C + e] : (e - N_EDGES_C);
        atomicAdd(&deg[d], 1);
    }
}

// per-block exclusive scan (wave shuffles + tiny LDS), 196 blocks
__global__ __launch_bounds__(256) void scan_blocks(const int* __restrict__ deg,
                                                   int* __restrict__ excl,
                                                   int* __restrict__ blksum) {
    int t = threadIdx.x, b = blockIdx.x;
    int i = b * 256 + t;
    int v = (i < N_NODES_C) ? deg[i] : 0;
    int lane = t & 63, w = t >> 6;
    int inc = wave_incl_scan(v, lane);
    __shared__ int wt[4];
    if (lane == 63) wt[w] = inc;
    __syncthreads();
    int add = 0;
    for (int k = 0; k < w; ++k) add += wt[k];
    inc += add;
    if (i < N_NODES_C) excl[i] = inc - v;
    if (t == 255) blksum[b] = inc;
}

// single small block scans the 196 block sums
__global__ __launch_bounds__(256) void scan_tops(const int* __restrict__ blksum,
                                                 int* __restrict__ blkoff,
                                                 int* __restrict__ row_ptr) {
    __shared__ int s[256];
    int t = threadIdx.x;
    int v = (t < NBLK_SCAN) ? blksum[t] : 0;
    s[t] = v;
    __syncthreads();
    for (int off = 1; off < 256; off <<= 1) {
        int a = (t >= off) ? s[t - off] : 0;
        __syncthreads();
        s[t] += a;
        __syncthreads();
    }
    if (t < NBLK_SCAN) blkoff[t] = s[t] - v;
    if (t == 255) row_ptr[N_NODES_C] = s[255];   // == E_TOT_C
}

// write row_ptr + cursor, and graph boundaries from sorted batch
__global__ __launch_bounds__(256) void finalize_kernel(
    const int* __restrict__ excl, const int* __restrict__ blkoff,
    const int* __restrict__ batch, int* __restrict__ row_ptr,
    int* __restrict__ cursor, int* __restrict__ gstart) {
    int i = blockIdx.x * 256 + threadIdx.x;
    if (i >= N_NODES_C) return;
    int rp = excl[i] + blkoff[blockIdx.x];
    row_ptr[i] = rp;
    cursor[i] = rp;
    int bcur = batch[i];
    int bprev = (i > 0) ? batch[i - 1] : -1;
    for (int g = bprev + 1; g <= bcur; ++g) gstart[g] = i;
    if (i == N_NODES_C - 1)
        for (int g = bcur + 1; g <= N_GRAPHS_C; ++g) gstart[g] = N_NODES_C;
}

__global__ void scatter_kernel(const int* __restrict__ ei, int* __restrict__ cursor,
                               int* __restrict__ csr_src) {
    int stride = gridDim.x * blockDim.x;
    for (int e = blockIdx.x * blockDim.x + threadIdx.x; e < E_TOT_C; e += stride) {
        int s_, d_;
        if (e < N_EDGES_C) { s_ = ei[e]; d_ = ei[N_EDGES_C + e]; }
        else               { s_ = d_ = e - N_EDGES_C; }
        int pos = atomicAdd(&cursor[d_], 1);
        csr_src[pos] = s_;
    }
}

// ---------------- per-layer kernels ----------------

// h = x @ W fused with alpha_src/alpha_dst dots; wave-per-node
__global__ __launch_bounds__(256) void transform_kernel(
    const float* __restrict__ xin, const float* __restrict__ W,
    const float* __restrict__ a_s, const float* __restrict__ a_d,
    float* __restrict__ hout, float* __restrict__ as_out, float* __restrict__ ad_out)
{
    __shared__ float Wl[64][64];
    __shared__ float xs[4][64];
    __shared__ float asv[64], adv[64];
    int t = threadIdx.x;
    for (int i = t; i < 64 * 64; i += 256) Wl[i >> 6][i & 63] = W[i];
    if (t < 64) { asv[t] = a_s[t]; adv[t] = a_d[t]; }
    int w = t >> 6, c = t & 63;
    int n = blockIdx.x * 4 + w;      // 50000 % 4 == 0
    xs[w][c] = xin[n * CH + c];
    __syncthreads();
    float acc = 0.f;
#pragma unroll
    for (int k = 0; k < 64; ++k) acc = fmaf(xs[w][k], Wl[k][c], acc);
    hout[n * CH + c] = acc;
    float vs = wave_reduce_sum(acc * asv[c]);
    float vd = wave_reduce_sum(acc * adv[c]);
    if (c == 0) { as_out[n] = vs; ad_out[n] = vd; }
}

// segment softmax + weighted aggregation + bias + ELU; wave-per-dst-node.
// Fast path (deg<=64, essentially always for Poisson(17)): edge state lives in
// one register per lane, phase 3 broadcasts it via shuffles — no csr_ex buffer,
// one random gather pass instead of two.
__global__ __launch_bounds__(256) void aggregate_kernel(
    const float* __restrict__ h, const float* __restrict__ as,
    const float* __restrict__ ad, const float* __restrict__ bias,
    const int* __restrict__ row_ptr, const int* __restrict__ csr_src,
    float* __restrict__ out)
{
    int t = threadIdx.x;
    int w = t >> 6, lane = t & 63;
    int n = blockIdx.x * 4 + w;
    int beg = row_ptr[n], end = row_ptr[n + 1];
    int deg = end - beg;             // >= 1 (self-loop)
    float adn = ad[n];
    float acc = 0.f, inv;
    if (deg <= 64) {
        int s_reg = csr_src[beg + min(lane, deg - 1)];   // coalesced
        float l = -1e30f;
        if (lane < deg) {
            float v = as[s_reg] + adn;                   // one random 4B gather
            l = (v >= 0.f) ? v : 0.2f * v;
        }
        float m = wave_reduce_max(l);
        float ex = (lane < deg) ? expf(l - m) : 0.f;
        float ssum = wave_reduce_sum(ex);
        inv = 1.f / fmaxf(ssum, 1e-16f);
        int j = 0;
        for (; j + 4 <= deg; j += 4) {
            int   s0 = __shfl(s_reg, j, 64),     s1 = __shfl(s_reg, j + 1, 64);
            int   s2 = __shfl(s_reg, j + 2, 64), s3 = __shfl(s_reg, j + 3, 64);
            float w0 = __shfl(ex, j, 64),        w1 = __shfl(ex, j + 1, 64);
            float w2 = __shfl(ex, j + 2, 64),    w3 = __shfl(ex, j + 3, 64);
            float v0 = h[(size_t)s0 * CH + lane];
            float v1 = h[(size_t)s1 * CH + lane];
            float v2 = h[(size_t)s2 * CH + lane];
            float v3 = h[(size_t)s3 * CH + lane];
            acc = fmaf(w0, v0, acc); acc = fmaf(w1, v1, acc);
            acc = fmaf(w2, v2, acc); acc = fmaf(w3, v3, acc);
        }
        for (; j < deg; ++j) {
            int s = __shfl(s_reg, j, 64);
            float ww = __shfl(ex, j, 64);
            acc = fmaf(ww, h[(size_t)s * CH + lane], acc);
        }
    } else {
        // rare fallback: 3-pass with logit recompute (no scratch buffer)
        float m = -1e30f;
        for (int i = beg + lane; i < end; i += 64) {
            float v = as[csr_src[i]] + adn;
            v = (v >= 0.f) ? v : 0.2f * v;
            m = fmaxf(m, v);
        }
        m = wave_reduce_max(m);
        float ssum = 0.f;
        for (int i = beg + lane; i < end; i += 64) {
            float v = as[csr_src[i]] + adn;
            v = (v >= 0.f) ? v : 0.2f * v;
            ssum += expf(v - m);
        }
        ssum = wave_reduce_sum(ssum);
        inv = 1.f / fmaxf(ssum, 1e-16f);
        for (int i = beg; i < end; ++i) {
            int s = csr_src[i];
            float v = as[s] + adn;
            v = (v >= 0.f) ? v : 0.2f * v;
            float ww = expf(v - m);
            acc = fmaf(ww, h[(size_t)s * CH + lane], acc);
        }
    }
    acc = acc * inv + bias[lane];
    out[n * CH + lane] = (acc > 0.f) ? acc : expm1f(acc);
}

// ---------------- pooling (atomic-free, fused divide) ----------------

__global__ __launch_bounds__(256) void pool_kernel(
    const float* __restrict__ h, const int* __restrict__ gstart,
    float* __restrict__ out)
{
    __shared__ float red[4][64];
    int g = blockIdx.x;
    int t = threadIdx.x, w = t >> 6, lane = t & 63;
    int beg = gstart[g], end = gstart[g + 1];
    float acc = 0.f;
    for (int n = beg + w; n < end; n += 4) acc += h[n * CH + lane];
    red[w][lane] = acc;
    __syncthreads();
    if (w == 0) {
        float v = red[0][lane] + red[1][lane] + red[2][lane] + red[3][lane];
        float c = (float)(end - beg);
        out[g * CH + lane] = v / fmaxf(c, 1.f);
    }
}

// ---------------- launch ----------------

extern "C" void kernel_launch(void* const* d_in, const int* in_sizes, int n_in,
                              void* d_out, int out_size, void* d_ws, size_t ws_size,
                              hipStream_t stream)
{
    const float* x   = (const float*)d_in[0];
    const int*   ei  = (const int*)d_in[1];
    const int*   bat = (const int*)d_in[2];
    const float* W1  = (const float*)d_in[3];
    const float* as1 = (const float*)d_in[4];
    const float* ad1 = (const float*)d_in[5];
    const float* b1  = (const float*)d_in[6];
    const float* W2  = (const float*)d_in[7];
    const float* as2 = (const float*)d_in[8];
    const float* ad2 = (const float*)d_in[9];
    const float* b2  = (const float*)d_in[10];
    float* out = (float*)d_out;

    char* ws = (char*)d_ws;
    size_t off = 0;
    auto alloc = [&](size_t bytes) -> void* {
        void* p = ws + off;
        off += (bytes + 255) & ~size_t(255);
        return p;
    };
    float* hbuf    = (float*)alloc(sizeof(float) * N_NODES_C * CH);
    float* obuf    = (float*)alloc(sizeof(float) * N_NODES_C * CH);
    float* alpha_s = (float*)alloc(sizeof(float) * N_NODES_C);
    float* alpha_d = (float*)alloc(sizeof(float) * N_NODES_C);
    int*   deg_buf = (int*)alloc(sizeof(int) * N_NODES_C);
    int*   excl    = (int*)alloc(sizeof(int) * N_NODES_C);
    int*   blksum  = (int*)alloc(sizeof(int) * NBLK_SCAN);
    int*   blkoff  = (int*)alloc(sizeof(int) * NBLK_SCAN);
    int*   row_ptr = (int*)alloc(sizeof(int) * (N_NODES_C + 1));
    int*   cursor  = (int*)alloc(sizeof(int) * N_NODES_C);
    int*   csr_src = (int*)alloc(sizeof(int) * E_TOT_C);
    int*   gstart  = (int*)alloc(sizeof(int) * (N_GRAPHS_C + 1));

    const int NB = N_NODES_C / 4;   // 12500 blocks, 4 waves (nodes) per block

    // CSR build (shared by both layers) + graph boundaries
    hipMemsetAsync(deg_buf, 0, sizeof(int) * N_NODES_C, stream);
    hist_kernel<<<1024, 256, 0, stream>>>(ei, deg_buf);
    scan_blocks<<<NBLK_SCAN, 256, 0, stream>>>(deg_buf, excl, blksum);
    scan_tops<<<1, 256, 0, stream>>>(blksum, blkoff, row_ptr);
    finalize_kernel<<<NBLK_SCAN, 256, 0, stream>>>(excl, blkoff, bat,
                                                   row_ptr, cursor, gstart);
    scatter_kernel<<<1024, 256, 0, stream>>>(ei, cursor, csr_src);

    // layer 1
    transform_kernel<<<NB, 256, 0, stream>>>(x, W1, as1, ad1, hbuf, alpha_s, alpha_d);
    aggregate_kernel<<<NB, 256, 0, stream>>>(hbuf, alpha_s, alpha_d, b1,
                                             row_ptr, csr_src, obuf);
    // layer 2
    transform_kernel<<<NB, 256, 0, stream>>>(obuf, W2, as2, ad2, hbuf, alpha_s, alpha_d);
    aggregate_kernel<<<NB, 256, 0, stream>>>(hbuf, alpha_s, alpha_d, b2,
                                             row_ptr, csr_src, obuf);

    // global mean pool
    pool_kernel<<<N_GRAPHS_C, 256, 0, stream>>>(obuf, gstart, out);
}

// Round 3
// 266.533 us; speedup vs baseline: 2.2787x; 1.2621x over previous
//
#include <hip/hip_runtime.h>
#include <hip/hip_bf16.h>
#include <math.h>

#define N_NODES_C 50000
#define N_EDGES_C 800000
#define E_TOT_C   (N_EDGES_C + N_NODES_C)   // 850000 incl. self-loops
#define N_GRAPHS_C 512
#define CH 64
#define NBUCK 391        // dst >> 7 -> 391 buckets of <=128 nodes
#define NB_BUCK 160      // blocks for bucket count/write passes
#define BCAP 3328        // max edges per bucket (mean 2176, sigma ~47; 24-sigma headroom)

__device__ __forceinline__ float wave_reduce_sum(float v) {
#pragma unroll
    for (int m = 32; m >= 1; m >>= 1) v += __shfl_xor(v, m, 64);
    return v;
}
__device__ __forceinline__ float wave_reduce_max(float v) {
#pragma unroll
    for (int m = 32; m >= 1; m >>= 1) v = fmaxf(v, __shfl_xor(v, m, 64));
    return v;
}

// ---------------- CSR build via bucketed counting sort ----------------

__global__ __launch_bounds__(256) void bucket_count(const int* __restrict__ ei,
                                                    int* __restrict__ bucket_size,
                                                    int* __restrict__ blk_base) {
    __shared__ int cnt[NBUCK];
    int t = threadIdx.x, blk = blockIdx.x;
    for (int i = t; i < NBUCK; i += 256) cnt[i] = 0;
    __syncthreads();
    const int CHUNK = (E_TOT_C + NB_BUCK - 1) / NB_BUCK;
    int beg = blk * CHUNK, end = min(beg + CHUNK, E_TOT_C);
    for (int e = beg + t; e < end; e += 256) {
        int d = (e < N_EDGES_C) ? ei[N_EDGES_C + e] : (e - N_EDGES_C);
        atomicAdd(&cnt[d >> 7], 1);
    }
    __syncthreads();
    for (int b = t; b < NBUCK; b += 256)
        blk_base[blk * NBUCK + b] = atomicAdd(&bucket_size[b], cnt[b]);
}

__global__ __launch_bounds__(512) void scan_buckets(const int* __restrict__ bucket_size,
                                                    int* __restrict__ bucket_base) {
    __shared__ int s[512];
    int t = threadIdx.x;
    int v = (t < NBUCK) ? bucket_size[t] : 0;
    s[t] = v;
    __syncthreads();
    for (int off = 1; off < 512; off <<= 1) {
        int a = (t >= off) ? s[t - off] : 0;
        __syncthreads();
        s[t] += a;
        __syncthreads();
    }
    if (t < NBUCK) bucket_base[t] = s[t] - v;
    if (t == 511) bucket_base[NBUCK] = s[511];   // == E_TOT_C
}

__global__ __launch_bounds__(256) void bucket_write(const int* __restrict__ ei,
                                                    const int* __restrict__ bucket_base,
                                                    const int* __restrict__ blk_base,
                                                    unsigned int* __restrict__ buck_edges) {
    __shared__ int lcur[NBUCK];
    __shared__ int lbase[NBUCK];
    int t = threadIdx.x, blk = blockIdx.x;
    for (int i = t; i < NBUCK; i += 256) {
        lcur[i] = 0;
        lbase[i] = bucket_base[i] + blk_base[blk * NBUCK + i];
    }
    __syncthreads();
    const int CHUNK = (E_TOT_C + NB_BUCK - 1) / NB_BUCK;
    int beg = blk * CHUNK, end = min(beg + CHUNK, E_TOT_C);
    for (int e = beg + t; e < end; e += 256) {
        int s_, d_;
        if (e < N_EDGES_C) { s_ = ei[e]; d_ = ei[N_EDGES_C + e]; }
        else               { s_ = d_ = e - N_EDGES_C; }
        int b = d_ >> 7;
        int pos = atomicAdd(&lcur[b], 1);
        buck_edges[lbase[b] + pos] = ((unsigned)d_ << 16) | (unsigned)s_;
    }
}

// one block per bucket: build per-node CSR fully in LDS, write coalesced
__global__ __launch_bounds__(256) void bucket_to_csr(const unsigned int* __restrict__ buck_edges,
                                                     const int* __restrict__ bucket_base,
                                                     int* __restrict__ csr_src,
                                                     int* __restrict__ row_ptr) {
    __shared__ unsigned int ebuf[BCAP];
    __shared__ int sbuf[BCAP];
    __shared__ int deg[128], sc[128], off[128], cur[128];
    int bb = blockIdx.x, t = threadIdx.x;
    int base = bucket_base[bb];
    int size = min(bucket_base[bb + 1] - base, BCAP);
    int node0 = bb << 7;
    int nnodes = min(128, N_NODES_C - node0);
    for (int i = t; i < size; i += 256) ebuf[i] = buck_edges[base + i];
    if (t < 128) deg[t] = 0;
    __syncthreads();
    for (int i = t; i < size; i += 256) atomicAdd(&deg[(ebuf[i] >> 16) & 127], 1);
    __syncthreads();
    if (t < 128) sc[t] = deg[t];
    __syncthreads();
    for (int o = 1; o < 128; o <<= 1) {
        int a = (t < 128 && t >= o) ? sc[t - o] : 0;
        __syncthreads();
        if (t < 128) sc[t] += a;
        __syncthreads();
    }
    if (t < 128) { off[t] = sc[t] - deg[t]; cur[t] = 0; }
    __syncthreads();
    for (int i = t; i < size; i += 256) {
        unsigned pk = ebuf[i];
        int l = (pk >> 16) & 127;
        int p = atomicAdd(&cur[l], 1);
        sbuf[off[l] + p] = (int)(pk & 0xFFFFu);
    }
    __syncthreads();
    for (int i = t; i < size; i += 256) csr_src[base + i] = sbuf[i];
    if (t < nnodes) row_ptr[node0 + t] = base + off[t];
    if (bb == 0 && t == 0) row_ptr[N_NODES_C] = E_TOT_C;
}

// graph boundaries from sorted batch
__global__ __launch_bounds__(256) void gstart_kernel(const int* __restrict__ batch,
                                                     int* __restrict__ gstart) {
    int i = blockIdx.x * 256 + threadIdx.x;
    if (i >= N_NODES_C) return;
    int bcur = batch[i];
    int bprev = (i > 0) ? batch[i - 1] : -1;
    for (int g = bprev + 1; g <= bcur; ++g) gstart[g] = i;
    if (i == N_NODES_C - 1)
        for (int g = bcur + 1; g <= N_GRAPHS_C; ++g) gstart[g] = N_NODES_C;
}

// ---------------- per-layer kernels ----------------

// h = x @ W fused with alpha dots; wave-per-node; h stored bf16 for the gather
__global__ __launch_bounds__(256) void transform_kernel(
    const float* __restrict__ xin, const float* __restrict__ W,
    const float* __restrict__ a_s, const float* __restrict__ a_d,
    __hip_bfloat16* __restrict__ hout, float* __restrict__ as_out,
    float* __restrict__ ad_out)
{
    __shared__ float Wl[64][64];
    __shared__ float xs[4][64];
    __shared__ float asv[64], adv[64];
    int t = threadIdx.x;
    for (int i = t; i < 64 * 64; i += 256) Wl[i >> 6][i & 63] = W[i];
    if (t < 64) { asv[t] = a_s[t]; adv[t] = a_d[t]; }
    int w = t >> 6, c = t & 63;
    int n = blockIdx.x * 4 + w;      // 50000 % 4 == 0
    xs[w][c] = xin[n * CH + c];
    __syncthreads();
    float acc = 0.f;
#pragma unroll
    for (int k = 0; k < 64; ++k) acc = fmaf(xs[w][k], Wl[k][c], acc);
    hout[n * CH + c] = __float2bfloat16(acc);
    float vs = wave_reduce_sum(acc * asv[c]);   // alphas from full-precision acc
    float vd = wave_reduce_sum(acc * adv[c]);
    if (c == 0) { as_out[n] = vs; ad_out[n] = vd; }
}

// segment softmax + weighted aggregation + bias + ELU; wave-per-dst-node
__global__ __launch_bounds__(256) void aggregate_kernel(
    const __hip_bfloat16* __restrict__ h, const float* __restrict__ as,
    const float* __restrict__ ad, const float* __restrict__ bias,
    const int* __restrict__ row_ptr, const int* __restrict__ csr_src,
    float* __restrict__ out)
{
    int t = threadIdx.x;
    int w = t >> 6, lane = t & 63;
    int n = blockIdx.x * 4 + w;
    int beg = row_ptr[n], end = row_ptr[n + 1];
    int deg = end - beg;             // >= 1 (self-loop)
    float adn = ad[n];
    float acc = 0.f, inv;
    if (deg <= 64) {
        int s_reg = csr_src[beg + min(lane, deg - 1)];   // coalesced
        float l = -1e30f;
        if (lane < deg) {
            float v = as[s_reg] + adn;                   // one random 4B gather
            l = (v >= 0.f) ? v : 0.2f * v;
        }
        float m = wave_reduce_max(l);
        float ex = (lane < deg) ? expf(l - m) : 0.f;
        float ssum = wave_reduce_sum(ex);
        inv = 1.f / fmaxf(ssum, 1e-16f);
        int j = 0;
        for (; j + 4 <= deg; j += 4) {
            int   s0 = __shfl(s_reg, j, 64),     s1 = __shfl(s_reg, j + 1, 64);
            int   s2 = __shfl(s_reg, j + 2, 64), s3 = __shfl(s_reg, j + 3, 64);
            float w0 = __shfl(ex, j, 64),        w1 = __shfl(ex, j + 1, 64);
            float w2 = __shfl(ex, j + 2, 64),    w3 = __shfl(ex, j + 3, 64);
            float v0 = __bfloat162float(h[(size_t)s0 * CH + lane]);
            float v1 = __bfloat162float(h[(size_t)s1 * CH + lane]);
            float v2 = __bfloat162float(h[(size_t)s2 * CH + lane]);
            float v3 = __bfloat162float(h[(size_t)s3 * CH + lane]);
            acc = fmaf(w0, v0, acc); acc = fmaf(w1, v1, acc);
            acc = fmaf(w2, v2, acc); acc = fmaf(w3, v3, acc);
        }
        for (; j < deg; ++j) {
            int s = __shfl(s_reg, j, 64);
            float ww = __shfl(ex, j, 64);
            acc = fmaf(ww, __bfloat162float(h[(size_t)s * CH + lane]), acc);
        }
    } else {
        // rare fallback: recompute logits, no scratch
        float m = -1e30f;
        for (int i = beg + lane; i < end; i += 64) {
            float v = as[csr_src[i]] + adn;
            v = (v >= 0.f) ? v : 0.2f * v;
            m = fmaxf(m, v);
        }
        m = wave_reduce_max(m);
        float ssum = 0.f;
        for (int i = beg + lane; i < end; i += 64) {
            float v = as[csr_src[i]] + adn;
            v = (v >= 0.f) ? v : 0.2f * v;
            ssum += expf(v - m);
        }
        ssum = wave_reduce_sum(ssum);
        inv = 1.f / fmaxf(ssum, 1e-16f);
        for (int i = beg; i < end; ++i) {
            int s = csr_src[i];
            float v = as[s] + adn;
            v = (v >= 0.f) ? v : 0.2f * v;
            float ww = expf(v - m);
            acc = fmaf(ww, __bfloat162float(h[(size_t)s * CH + lane]), acc);
        }
    }
    acc = acc * inv + bias[lane];
    out[n * CH + lane] = (acc > 0.f) ? acc : expm1f(acc);
}

// ---------------- pooling (atomic-free, fused divide) ----------------

__global__ __launch_bounds__(256) void pool_kernel(
    const float* __restrict__ h, const int* __restrict__ gstart,
    float* __restrict__ out)
{
    __shared__ float red[4][64];
    int g = blockIdx.x;
    int t = threadIdx.x, w = t >> 6, lane = t & 63;
    int beg = gstart[g], end = gstart[g + 1];
    float acc = 0.f;
    for (int n = beg + w; n < end; n += 4) acc += h[n * CH + lane];
    red[w][lane] = acc;
    __syncthreads();
    if (w == 0) {
        float v = red[0][lane] + red[1][lane] + red[2][lane] + red[3][lane];
        float c = (float)(end - beg);
        out[g * CH + lane] = v / fmaxf(c, 1.f);
    }
}

// ---------------- launch ----------------

extern "C" void kernel_launch(void* const* d_in, const int* in_sizes, int n_in,
                              void* d_out, int out_size, void* d_ws, size_t ws_size,
                              hipStream_t stream)
{
    const float* x   = (const float*)d_in[0];
    const int*   ei  = (const int*)d_in[1];
    const int*   bat = (const int*)d_in[2];
    const float* W1  = (const float*)d_in[3];
    const float* as1 = (const float*)d_in[4];
    const float* ad1 = (const float*)d_in[5];
    const float* b1  = (const float*)d_in[6];
    const float* W2  = (const float*)d_in[7];
    const float* as2 = (const float*)d_in[8];
    const float* ad2 = (const float*)d_in[9];
    const float* b2  = (const float*)d_in[10];
    float* out = (float*)d_out;

    char* ws = (char*)d_ws;
    size_t off = 0;
    auto alloc = [&](size_t bytes) -> void* {
        void* p = ws + off;
        off += (bytes + 255) & ~size_t(255);
        return p;
    };
    __hip_bfloat16* hbuf = (__hip_bfloat16*)alloc(sizeof(__hip_bfloat16) * N_NODES_C * CH);
    float* obuf    = (float*)alloc(sizeof(float) * N_NODES_C * CH);
    float* alpha_s = (float*)alloc(sizeof(float) * N_NODES_C);
    float* alpha_d = (float*)alloc(sizeof(float) * N_NODES_C);
    int*   bucket_size = (int*)alloc(sizeof(int) * NBUCK);
    int*   bucket_base = (int*)alloc(sizeof(int) * (NBUCK + 1));
    int*   blk_base    = (int*)alloc(sizeof(int) * NB_BUCK * NBUCK);
    unsigned int* buck_edges = (unsigned int*)alloc(sizeof(unsigned) * E_TOT_C);
    int*   csr_src = (int*)alloc(sizeof(int) * E_TOT_C);
    int*   row_ptr = (int*)alloc(sizeof(int) * (N_NODES_C + 1));
    int*   gstart  = (int*)alloc(sizeof(int) * (N_GRAPHS_C + 1));

    const int NB = N_NODES_C / 4;   // 12500 blocks, 4 waves (nodes) per block

    // CSR build (counting sort; all global writes coalesced or L2-merged)
    hipMemsetAsync(bucket_size, 0, sizeof(int) * NBUCK, stream);
    bucket_count<<<NB_BUCK, 256, 0, stream>>>(ei, bucket_size, blk_base);
    scan_buckets<<<1, 512, 0, stream>>>(bucket_size, bucket_base);
    bucket_write<<<NB_BUCK, 256, 0, stream>>>(ei, bucket_base, blk_base, buck_edges);
    bucket_to_csr<<<NBUCK, 256, 0, stream>>>(buck_edges, bucket_base, csr_src, row_ptr);
    gstart_kernel<<<196, 256, 0, stream>>>(bat, gstart);

    // layer 1
    transform_kernel<<<NB, 256, 0, stream>>>(x, W1, as1, ad1, hbuf, alpha_s, alpha_d);
    aggregate_kernel<<<NB, 256, 0, stream>>>(hbuf, alpha_s, alpha_d, b1,
                                             row_ptr, csr_src, obuf);
    // layer 2
    transform_kernel<<<NB, 256, 0, stream>>>(obuf, W2, as2, ad2, hbuf, alpha_s, alpha_d);
    aggregate_kernel<<<NB, 256, 0, stream>>>(hbuf, alpha_s, alpha_d, b2,
                                             row_ptr, csr_src, obuf);

    // global mean pool
    pool_kernel<<<N_GRAPHS_C, 256, 0, stream>>>(obuf, gstart, out);
}

// Round 4
// 246.042 us; speedup vs baseline: 2.4685x; 1.0833x over previous
//
#include <hip/hip_runtime.h>
#include <hip/hip_bf16.h>
#include <math.h>

#define N_NODES_C 50000
#define N_EDGES_C 800000
#define E_TOT_C   (N_EDGES_C + N_NODES_C)   // 850000 incl. self-loops
#define N_GRAPHS_C 512
#define CH 64
#define NBUCK 391        // dst >> 7 -> 391 buckets of <=128 nodes
#define NB_BUCK 160      // blocks for bucket count/write passes
#define BCAP 3328        // max edges per bucket (mean 2176; huge headroom)

__device__ __forceinline__ float wave_reduce_sum(float v) {
#pragma unroll
    for (int m = 32; m >= 1; m >>= 1) v += __shfl_xor(v, m, 64);
    return v;
}
__device__ __forceinline__ float wave_reduce_max(float v) {
#pragma unroll
    for (int m = 32; m >= 1; m >>= 1) v = fmaxf(v, __shfl_xor(v, m, 64));
    return v;
}

// ---------------- CSR build via bucketed counting sort ----------------

__global__ __launch_bounds__(256) void bucket_count(const int* __restrict__ ei,
                                                    int* __restrict__ bucket_size,
                                                    int* __restrict__ blk_base) {
    __shared__ int cnt[NBUCK];
    int t = threadIdx.x, blk = blockIdx.x;
    for (int i = t; i < NBUCK; i += 256) cnt[i] = 0;
    __syncthreads();
    const int CHUNK = (E_TOT_C + NB_BUCK - 1) / NB_BUCK;
    int beg = blk * CHUNK, end = min(beg + CHUNK, E_TOT_C);
    for (int e = beg + t; e < end; e += 256) {
        int d = (e < N_EDGES_C) ? ei[N_EDGES_C + e] : (e - N_EDGES_C);
        atomicAdd(&cnt[d >> 7], 1);
    }
    __syncthreads();
    for (int b = t; b < NBUCK; b += 256)
        blk_base[blk * NBUCK + b] = atomicAdd(&bucket_size[b], cnt[b]);
}

__global__ __launch_bounds__(512) void scan_buckets(const int* __restrict__ bucket_size,
                                                    int* __restrict__ bucket_base) {
    __shared__ int s[512];
    int t = threadIdx.x;
    int v = (t < NBUCK) ? bucket_size[t] : 0;
    s[t] = v;
    __syncthreads();
    for (int off = 1; off < 512; off <<= 1) {
        int a = (t >= off) ? s[t - off] : 0;
        __syncthreads();
        s[t] += a;
        __syncthreads();
    }
    if (t < NBUCK) bucket_base[t] = s[t] - v;
    if (t == 511) bucket_base[NBUCK] = s[511];   // == E_TOT_C
}

__global__ __launch_bounds__(256) void bucket_write(const int* __restrict__ ei,
                                                    const int* __restrict__ bucket_base,
                                                    const int* __restrict__ blk_base,
                                                    unsigned int* __restrict__ buck_edges) {
    __shared__ int lcur[NBUCK];
    __shared__ int lbase[NBUCK];
    int t = threadIdx.x, blk = blockIdx.x;
    for (int i = t; i < NBUCK; i += 256) {
        lcur[i] = 0;
        lbase[i] = bucket_base[i] + blk_base[blk * NBUCK + i];
    }
    __syncthreads();
    const int CHUNK = (E_TOT_C + NB_BUCK - 1) / NB_BUCK;
    int beg = blk * CHUNK, end = min(beg + CHUNK, E_TOT_C);
    for (int e = beg + t; e < end; e += 256) {
        int s_, d_;
        if (e < N_EDGES_C) { s_ = ei[e]; d_ = ei[N_EDGES_C + e]; }
        else               { s_ = d_ = e - N_EDGES_C; }
        int b = d_ >> 7;
        int pos = atomicAdd(&lcur[b], 1);
        buck_edges[lbase[b] + pos] = ((unsigned)d_ << 16) | (unsigned)s_;
    }
}

// one block per bucket: build per-node CSR fully in LDS, write coalesced
__global__ __launch_bounds__(256) void bucket_to_csr(const unsigned int* __restrict__ buck_edges,
                                                     const int* __restrict__ bucket_base,
                                                     unsigned short* __restrict__ csr_src,
                                                     int* __restrict__ row_ptr) {
    __shared__ unsigned int ebuf[BCAP];
    __shared__ unsigned short sbuf[BCAP];
    __shared__ int deg[128], sc[128], off[128], cur[128];
    int bb = blockIdx.x, t = threadIdx.x;
    int base = bucket_base[bb];
    int size = min(bucket_base[bb + 1] - base, BCAP);
    int node0 = bb << 7;
    int nnodes = min(128, N_NODES_C - node0);
    for (int i = t; i < size; i += 256) ebuf[i] = buck_edges[base + i];
    if (t < 128) deg[t] = 0;
    __syncthreads();
    for (int i = t; i < size; i += 256) atomicAdd(&deg[(ebuf[i] >> 16) & 127], 1);
    __syncthreads();
    if (t < 128) sc[t] = deg[t];
    __syncthreads();
    for (int o = 1; o < 128; o <<= 1) {
        int a = (t < 128 && t >= o) ? sc[t - o] : 0;
        __syncthreads();
        if (t < 128) sc[t] += a;
        __syncthreads();
    }
    if (t < 128) { off[t] = sc[t] - deg[t]; cur[t] = 0; }
    __syncthreads();
    for (int i = t; i < size; i += 256) {
        unsigned pk = ebuf[i];
        int l = (pk >> 16) & 127;
        int p = atomicAdd(&cur[l], 1);
        sbuf[off[l] + p] = (unsigned short)(pk & 0xFFFFu);
    }
    __syncthreads();
    for (int i = t; i < size; i += 256) csr_src[base + i] = sbuf[i];
    if (t < nnodes) row_ptr[node0 + t] = base + off[t];
    if (bb == 0 && t == 0) row_ptr[N_NODES_C] = E_TOT_C;
}

// graph boundaries from sorted batch
__global__ __launch_bounds__(256) void gstart_kernel(const int* __restrict__ batch,
                                                     int* __restrict__ gstart) {
    int i = blockIdx.x * 256 + threadIdx.x;
    if (i >= N_NODES_C) return;
    int bcur = batch[i];
    int bprev = (i > 0) ? batch[i - 1] : -1;
    for (int g = bprev + 1; g <= bcur; ++g) gstart[g] = i;
    if (i == N_NODES_C - 1)
        for (int g = bcur + 1; g <= N_GRAPHS_C; ++g) gstart[g] = N_NODES_C;
}

// ---------------- per-layer kernels ----------------

// h = x @ W fused with alpha dots; 16 nodes/block (4 per wave), h stored bf16
__global__ __launch_bounds__(256) void transform_kernel(
    const float* __restrict__ xin, const float* __restrict__ W,
    const float* __restrict__ a_s, const float* __restrict__ a_d,
    __hip_bfloat16* __restrict__ hout, float* __restrict__ as_out,
    float* __restrict__ ad_out)
{
    __shared__ float Wl[64][64];     // [k][c]
    __shared__ float xs[16][64];
    __shared__ float asv[64], adv[64];
    int t = threadIdx.x;
    const float4* W4 = (const float4*)W;
    float4* Wl4 = (float4*)&Wl[0][0];
    for (int i = t; i < 1024; i += 256) Wl4[i] = W4[i];
    if (t < 64) { asv[t] = a_s[t]; adv[t] = a_d[t]; }
    int n0 = blockIdx.x * 16;        // 50000 % 16 == 0
    ((float4*)&xs[0][0])[t] = ((const float4*)(xin + (size_t)n0 * CH))[t];
    __syncthreads();
    int w = t >> 6, c = t & 63;
    int r0 = w * 4;
    float a0 = 0.f, a1 = 0.f, a2 = 0.f, a3 = 0.f;
#pragma unroll
    for (int k = 0; k < 64; ++k) {
        float wl = Wl[k][c];
        a0 = fmaf(xs[r0 + 0][k], wl, a0);
        a1 = fmaf(xs[r0 + 1][k], wl, a1);
        a2 = fmaf(xs[r0 + 2][k], wl, a2);
        a3 = fmaf(xs[r0 + 3][k], wl, a3);
    }
    size_t hb = (size_t)(n0 + r0) * CH + c;
    hout[hb + 0 * CH] = __float2bfloat16(a0);
    hout[hb + 1 * CH] = __float2bfloat16(a1);
    hout[hb + 2 * CH] = __float2bfloat16(a2);
    hout[hb + 3 * CH] = __float2bfloat16(a3);
    float av = asv[c], dv = adv[c];
    float s0 = wave_reduce_sum(a0 * av), d0 = wave_reduce_sum(a0 * dv);
    float s1 = wave_reduce_sum(a1 * av), d1 = wave_reduce_sum(a1 * dv);
    float s2 = wave_reduce_sum(a2 * av), d2 = wave_reduce_sum(a2 * dv);
    float s3 = wave_reduce_sum(a3 * av), d3 = wave_reduce_sum(a3 * dv);
    if (c == 0) {
        int n = n0 + r0;
        as_out[n + 0] = s0; ad_out[n + 0] = d0;
        as_out[n + 1] = s1; ad_out[n + 1] = d1;
        as_out[n + 2] = s2; ad_out[n + 2] = d2;
        as_out[n + 3] = s3; ad_out[n + 3] = d3;
    }
}

// segment softmax + weighted aggregation + bias + ELU; wave-per-dst-node.
// Fast path: 4 edges per iteration — lane l covers channel quad 4*(l&15) of
// edge j*4+(l>>4); one 8B load = 4 bf16; padded edges contribute weight 0.
__global__ __launch_bounds__(256) void aggregate_kernel(
    const __hip_bfloat16* __restrict__ h, const float* __restrict__ as,
    const float* __restrict__ ad, const float* __restrict__ bias,
    const int* __restrict__ row_ptr, const unsigned short* __restrict__ csr_src,
    float* __restrict__ out)
{
    int t = threadIdx.x;
    int w = t >> 6, lane = t & 63;
    int n = blockIdx.x * 4 + w;
    int beg = row_ptr[n], end = row_ptr[n + 1];
    int deg = end - beg;             // >= 1 (self-loop)
    float adn = ad[n];
    if (deg <= 64) {
        int s_reg = (int)csr_src[beg + min(lane, deg - 1)];   // coalesced 2B
        float l = -1e30f;
        if (lane < deg) {
            float v = as[s_reg] + adn;                        // random 4B gather
            l = (v >= 0.f) ? v : 0.2f * v;
        }
        float m = wave_reduce_max(l);
        float ex = (lane < deg) ? expf(l - m) : 0.f;          // 0 for pad lanes
        float ssum = wave_reduce_sum(ex);
        float inv = 1.f / fmaxf(ssum, 1e-16f);
        int sub = lane >> 4;          // which of 4 edges in the group
        int cg  = (lane & 15) << 2;   // channel quad base
        float a0 = 0.f, a1 = 0.f, a2 = 0.f, a3 = 0.f;
        int jmax = (deg + 3) >> 2;    // raw edge index never exceeds 63
        for (int j = 0; j < jmax; ++j) {
            int e = j * 4 + sub;
            int s = __shfl(s_reg, e, 64);
            float wgt = __shfl(ex, e, 64);    // 0 beyond deg
            uint2 u = *reinterpret_cast<const uint2*>(h + (size_t)s * CH + cg);
            a0 = fmaf(wgt, __uint_as_float(u.x << 16), a0);
            a1 = fmaf(wgt, __uint_as_float(u.x & 0xFFFF0000u), a1);
            a2 = fmaf(wgt, __uint_as_float(u.y << 16), a2);
            a3 = fmaf(wgt, __uint_as_float(u.y & 0xFFFF0000u), a3);
        }
#pragma unroll
        for (int m2 = 16; m2 <= 32; m2 <<= 1) {
            a0 += __shfl_xor(a0, m2, 64);
            a1 += __shfl_xor(a1, m2, 64);
            a2 += __shfl_xor(a2, m2, 64);
            a3 += __shfl_xor(a3, m2, 64);
        }
        if (lane < 16) {
            float4 b = ((const float4*)bias)[lane];
            float4 o;
            o.x = a0 * inv + b.x; o.y = a1 * inv + b.y;
            o.z = a2 * inv + b.z; o.w = a3 * inv + b.w;
            o.x = (o.x > 0.f) ? o.x : expm1f(o.x);
            o.y = (o.y > 0.f) ? o.y : expm1f(o.y);
            o.z = (o.z > 0.f) ? o.z : expm1f(o.z);
            o.w = (o.w > 0.f) ? o.w : expm1f(o.w);
            ((float4*)(out + (size_t)n * CH))[lane] = o;
        }
    } else {
        // rare fallback: recompute logits, lane-per-channel
        float m = -1e30f;
        for (int i = beg + lane; i < end; i += 64) {
            float v = as[csr_src[i]] + adn;
            v = (v >= 0.f) ? v : 0.2f * v;
            m = fmaxf(m, v);
        }
        m = wave_reduce_max(m);
        float ssum = 0.f;
        for (int i = beg + lane; i < end; i += 64) {
            float v = as[csr_src[i]] + adn;
            v = (v >= 0.f) ? v : 0.2f * v;
            ssum += expf(v - m);
        }
        ssum = wave_reduce_sum(ssum);
        float inv = 1.f / fmaxf(ssum, 1e-16f);
        float acc = 0.f;
        for (int i = beg; i < end; ++i) {
            int s = csr_src[i];
            float v = as[s] + adn;
            v = (v >= 0.f) ? v : 0.2f * v;
            float ww = expf(v - m);
            acc = fmaf(ww, __bfloat162float(h[(size_t)s * CH + lane]), acc);
        }
        acc = acc * inv + bias[lane];
        out[n * CH + lane] = (acc > 0.f) ? acc : expm1f(acc);
    }
}

// ---------------- pooling (atomic-free, fused divide) ----------------

__global__ __launch_bounds__(256) void pool_kernel(
    const float* __restrict__ h, const int* __restrict__ gstart,
    float* __restrict__ out)
{
    __shared__ float red[4][64];
    int g = blockIdx.x;
    int t = threadIdx.x, w = t >> 6, lane = t & 63;
    int beg = gstart[g], end = gstart[g + 1];
    float acc = 0.f;
    for (int n = beg + w; n < end; n += 4) acc += h[n * CH + lane];
    red[w][lane] = acc;
    __syncthreads();
    if (w == 0) {
        float v = red[0][lane] + red[1][lane] + red[2][lane] + red[3][lane];
        float c = (float)(end - beg);
        out[g * CH + lane] = v / fmaxf(c, 1.f);
    }
}

// ---------------- launch ----------------

extern "C" void kernel_launch(void* const* d_in, const int* in_sizes, int n_in,
                              void* d_out, int out_size, void* d_ws, size_t ws_size,
                              hipStream_t stream)
{
    const float* x   = (const float*)d_in[0];
    const int*   ei  = (const int*)d_in[1];
    const int*   bat = (const int*)d_in[2];
    const float* W1  = (const float*)d_in[3];
    const float* as1 = (const float*)d_in[4];
    const float* ad1 = (const float*)d_in[5];
    const float* b1  = (const float*)d_in[6];
    const float* W2  = (const float*)d_in[7];
    const float* as2 = (const float*)d_in[8];
    const float* ad2 = (const float*)d_in[9];
    const float* b2  = (const float*)d_in[10];
    float* out = (float*)d_out;

    char* ws = (char*)d_ws;
    size_t off = 0;
    auto alloc = [&](size_t bytes) -> void* {
        void* p = ws + off;
        off += (bytes + 255) & ~size_t(255);
        return p;
    };
    __hip_bfloat16* hbuf = (__hip_bfloat16*)alloc(sizeof(__hip_bfloat16) * N_NODES_C * CH);
    float* obuf    = (float*)alloc(sizeof(float) * N_NODES_C * CH);
    float* alpha_s = (float*)alloc(sizeof(float) * N_NODES_C);
    float* alpha_d = (float*)alloc(sizeof(float) * N_NODES_C);
    int*   bucket_size = (int*)alloc(sizeof(int) * NBUCK);
    int*   bucket_base = (int*)alloc(sizeof(int) * (NBUCK + 1));
    int*   blk_base    = (int*)alloc(sizeof(int) * NB_BUCK * NBUCK);
    unsigned int* buck_edges = (unsigned int*)alloc(sizeof(unsigned) * E_TOT_C);
    unsigned short* csr_src = (unsigned short*)alloc(sizeof(unsigned short) * E_TOT_C);
    int*   row_ptr = (int*)alloc(sizeof(int) * (N_NODES_C + 1));
    int*   gstart  = (int*)alloc(sizeof(int) * (N_GRAPHS_C + 1));

    const int NB_AGG = N_NODES_C / 4;    // 12500 blocks, wave-per-node
    const int NB_TRF = N_NODES_C / 16;   // 3125 blocks, 16 nodes/block

    // CSR build (counting sort; writes coalesced or L2-merged)
    hipMemsetAsync(bucket_size, 0, sizeof(int) * NBUCK, stream);
    bucket_count<<<NB_BUCK, 256, 0, stream>>>(ei, bucket_size, blk_base);
    scan_buckets<<<1, 512, 0, stream>>>(bucket_size, bucket_base);
    bucket_write<<<NB_BUCK, 256, 0, stream>>>(ei, bucket_base, blk_base, buck_edges);
    bucket_to_csr<<<NBUCK, 256, 0, stream>>>(buck_edges, bucket_base, csr_src, row_ptr);
    gstart_kernel<<<196, 256, 0, stream>>>(bat, gstart);

    // layer 1
    transform_kernel<<<NB_TRF, 256, 0, stream>>>(x, W1, as1, ad1, hbuf, alpha_s, alpha_d);
    aggregate_kernel<<<NB_AGG, 256, 0, stream>>>(hbuf, alpha_s, alpha_d, b1,
                                                 row_ptr, csr_src, obuf);
    // layer 2
    transform_kernel<<<NB_TRF, 256, 0, stream>>>(obuf, W2, as2, ad2, hbuf, alpha_s, alpha_d);
    aggregate_kernel<<<NB_AGG, 256, 0, stream>>>(hbuf, alpha_s, alpha_d, b2,
                                                 row_ptr, csr_src, obuf);

    // global mean pool
    pool_kernel<<<N_GRAPHS_C, 256, 0, stream>>>(obuf, gstart, out);
}

// Round 5
// 244.686 us; speedup vs baseline: 2.4821x; 1.0055x over previous
//
#include <hip/hip_runtime.h>
#include <hip/hip_bf16.h>
#include <math.h>

#define N_NODES_C 50000
#define N_EDGES_C 800000
#define E_TOT_C   (N_EDGES_C + N_NODES_C)   // 850000 incl. self-loops
#define N_GRAPHS_C 512
#define CH 64
#define NBUCK 391        // dst >> 7 -> 391 buckets of <=128 nodes
#define NB_BUCK 160      // blocks for bucket count/write passes
#define BCAP 3328        // max edges per bucket (mean 2176; huge headroom)

__device__ __forceinline__ float wave_reduce_sum(float v) {
#pragma unroll
    for (int m = 32; m >= 1; m >>= 1) v += __shfl_xor(v, m, 64);
    return v;
}
__device__ __forceinline__ float wave_reduce_max(float v) {
#pragma unroll
    for (int m = 32; m >= 1; m >>= 1) v = fmaxf(v, __shfl_xor(v, m, 64));
    return v;
}

// ---------------- CSR build via bucketed counting sort ----------------

// graph boundaries from sorted batch; also zeroes bucket_size (blocks 0-1)
__global__ __launch_bounds__(256) void gstart_kernel(const int* __restrict__ batch,
                                                     int* __restrict__ gstart,
                                                     int* __restrict__ bucket_size) {
    int i = blockIdx.x * 256 + threadIdx.x;
    if (i < NBUCK) bucket_size[i] = 0;
    if (i >= N_NODES_C) return;
    int bcur = batch[i];
    int bprev = (i > 0) ? batch[i - 1] : -1;
    for (int g = bprev + 1; g <= bcur; ++g) gstart[g] = i;
    if (i == N_NODES_C - 1)
        for (int g = bcur + 1; g <= N_GRAPHS_C; ++g) gstart[g] = N_NODES_C;
}

__global__ __launch_bounds__(256) void bucket_count(const int* __restrict__ ei,
                                                    int* __restrict__ bucket_size,
                                                    int* __restrict__ blk_base) {
    __shared__ int cnt[NBUCK];
    int t = threadIdx.x, blk = blockIdx.x;
    for (int i = t; i < NBUCK; i += 256) cnt[i] = 0;
    __syncthreads();
    const int CHUNK = (E_TOT_C + NB_BUCK - 1) / NB_BUCK;
    int beg = blk * CHUNK, end = min(beg + CHUNK, E_TOT_C);
    for (int e = beg + t; e < end; e += 256) {
        int d = (e < N_EDGES_C) ? ei[N_EDGES_C + e] : (e - N_EDGES_C);
        atomicAdd(&cnt[d >> 7], 1);
    }
    __syncthreads();
    for (int b = t; b < NBUCK; b += 256)
        blk_base[blk * NBUCK + b] = atomicAdd(&bucket_size[b], cnt[b]);
}

__global__ __launch_bounds__(512) void scan_buckets(const int* __restrict__ bucket_size,
                                                    int* __restrict__ bucket_base) {
    __shared__ int s[512];
    int t = threadIdx.x;
    int v = (t < NBUCK) ? bucket_size[t] : 0;
    s[t] = v;
    __syncthreads();
    for (int off = 1; off < 512; off <<= 1) {
        int a = (t >= off) ? s[t - off] : 0;
        __syncthreads();
        s[t] += a;
        __syncthreads();
    }
    if (t < NBUCK) bucket_base[t] = s[t] - v;
    if (t == 511) bucket_base[NBUCK] = s[511];   // == E_TOT_C
}

__global__ __launch_bounds__(256) void bucket_write(const int* __restrict__ ei,
                                                    const int* __restrict__ bucket_base,
                                                    const int* __restrict__ blk_base,
                                                    unsigned int* __restrict__ buck_edges) {
    __shared__ int lcur[NBUCK];
    __shared__ int lbase[NBUCK];
    int t = threadIdx.x, blk = blockIdx.x;
    for (int i = t; i < NBUCK; i += 256) {
        lcur[i] = 0;
        lbase[i] = bucket_base[i] + blk_base[blk * NBUCK + i];
    }
    __syncthreads();
    const int CHUNK = (E_TOT_C + NB_BUCK - 1) / NB_BUCK;
    int beg = blk * CHUNK, end = min(beg + CHUNK, E_TOT_C);
    for (int e = beg + t; e < end; e += 256) {
        int s_, d_;
        if (e < N_EDGES_C) { s_ = ei[e]; d_ = ei[N_EDGES_C + e]; }
        else               { s_ = d_ = e - N_EDGES_C; }
        int b = d_ >> 7;
        int pos = atomicAdd(&lcur[b], 1);
        buck_edges[lbase[b] + pos] = ((unsigned)d_ << 16) | (unsigned)s_;
    }
}

// one block per bucket: build per-node CSR fully in LDS, write coalesced
__global__ __launch_bounds__(256) void bucket_to_csr(const unsigned int* __restrict__ buck_edges,
                                                     const int* __restrict__ bucket_base,
                                                     unsigned short* __restrict__ csr_src,
                                                     int* __restrict__ row_ptr) {
    __shared__ unsigned int ebuf[BCAP];
    __shared__ unsigned short sbuf[BCAP];
    __shared__ int deg[128], sc[128], off[128], cur[128];
    int bb = blockIdx.x, t = threadIdx.x;
    int base = bucket_base[bb];
    int size = min(bucket_base[bb + 1] - base, BCAP);
    int node0 = bb << 7;
    int nnodes = min(128, N_NODES_C - node0);
    for (int i = t; i < size; i += 256) ebuf[i] = buck_edges[base + i];
    if (t < 128) deg[t] = 0;
    __syncthreads();
    for (int i = t; i < size; i += 256) atomicAdd(&deg[(ebuf[i] >> 16) & 127], 1);
    __syncthreads();
    if (t < 128) sc[t] = deg[t];
    __syncthreads();
    for (int o = 1; o < 128; o <<= 1) {
        int a = (t < 128 && t >= o) ? sc[t - o] : 0;
        __syncthreads();
        if (t < 128) sc[t] += a;
        __syncthreads();
    }
    if (t < 128) { off[t] = sc[t] - deg[t]; cur[t] = 0; }
    __syncthreads();
    for (int i = t; i < size; i += 256) {
        unsigned pk = ebuf[i];
        int l = (pk >> 16) & 127;
        int p = atomicAdd(&cur[l], 1);
        sbuf[off[l] + p] = (unsigned short)(pk & 0xFFFFu);
    }
    __syncthreads();
    for (int i = t; i < size; i += 256) csr_src[base + i] = sbuf[i];
    if (t < nnodes) row_ptr[node0 + t] = base + off[t];
    if (bb == 0 && t == 0) row_ptr[N_NODES_C] = E_TOT_C;
}

// ---------------- per-layer kernels ----------------

// h = x @ W fused with alpha dots; 16 nodes/block (4 per wave), h stored bf16
__global__ __launch_bounds__(256) void transform_kernel(
    const float* __restrict__ xin, const float* __restrict__ W,
    const float* __restrict__ a_s, const float* __restrict__ a_d,
    __hip_bfloat16* __restrict__ hout, float* __restrict__ as_out,
    float* __restrict__ ad_out)
{
    __shared__ float Wl[64][64];     // [k][c]
    __shared__ float xs[16][64];
    __shared__ float asv[64], adv[64];
    int t = threadIdx.x;
    const float4* W4 = (const float4*)W;
    float4* Wl4 = (float4*)&Wl[0][0];
    for (int i = t; i < 1024; i += 256) Wl4[i] = W4[i];
    if (t < 64) { asv[t] = a_s[t]; adv[t] = a_d[t]; }
    int n0 = blockIdx.x * 16;        // 50000 % 16 == 0
    ((float4*)&xs[0][0])[t] = ((const float4*)(xin + (size_t)n0 * CH))[t];
    __syncthreads();
    int w = t >> 6, c = t & 63;
    int r0 = w * 4;
    float a0 = 0.f, a1 = 0.f, a2 = 0.f, a3 = 0.f;
#pragma unroll
    for (int k = 0; k < 64; ++k) {
        float wl = Wl[k][c];
        a0 = fmaf(xs[r0 + 0][k], wl, a0);
        a1 = fmaf(xs[r0 + 1][k], wl, a1);
        a2 = fmaf(xs[r0 + 2][k], wl, a2);
        a3 = fmaf(xs[r0 + 3][k], wl, a3);
    }
    size_t hb = (size_t)(n0 + r0) * CH + c;
    hout[hb + 0 * CH] = __float2bfloat16(a0);
    hout[hb + 1 * CH] = __float2bfloat16(a1);
    hout[hb + 2 * CH] = __float2bfloat16(a2);
    hout[hb + 3 * CH] = __float2bfloat16(a3);
    float av = asv[c], dv = adv[c];
    float s0 = wave_reduce_sum(a0 * av), d0 = wave_reduce_sum(a0 * dv);
    float s1 = wave_reduce_sum(a1 * av), d1 = wave_reduce_sum(a1 * dv);
    float s2 = wave_reduce_sum(a2 * av), d2 = wave_reduce_sum(a2 * dv);
    float s3 = wave_reduce_sum(a3 * av), d3 = wave_reduce_sum(a3 * dv);
    if (c == 0) {
        int n = n0 + r0;
        as_out[n + 0] = s0; ad_out[n + 0] = d0;
        as_out[n + 1] = s1; ad_out[n + 1] = d1;
        as_out[n + 2] = s2; ad_out[n + 2] = d2;
        as_out[n + 3] = s3; ad_out[n + 3] = d3;
    }
}

// segment softmax + weighted aggregation + bias + ELU; wave-per-dst-node.
// Fast path: 8 edges per iteration — lane l covers channel octet 8*(l&7) of
// edge j*8+(l>>3); one 16B uint4 load = 8 bf16 channels; padded slots are
// exec-masked out (no wasted loads).
__global__ __launch_bounds__(256) void aggregate_kernel(
    const __hip_bfloat16* __restrict__ h, const float* __restrict__ as,
    const float* __restrict__ ad, const float* __restrict__ bias,
    const int* __restrict__ row_ptr, const unsigned short* __restrict__ csr_src,
    float* __restrict__ out)
{
    int t = threadIdx.x;
    int w = t >> 6, lane = t & 63;
    int n = blockIdx.x * 4 + w;
    int beg = row_ptr[n], end = row_ptr[n + 1];
    int deg = end - beg;             // >= 1 (self-loop)
    float adn = ad[n];
    if (deg <= 64) {
        int s_reg = (int)csr_src[beg + min(lane, deg - 1)];   // coalesced 2B
        float l = -1e30f;
        if (lane < deg) {
            float v = as[s_reg] + adn;                        // random 4B gather
            l = (v >= 0.f) ? v : 0.2f * v;
        }
        float m = wave_reduce_max(l);
        float ex = (lane < deg) ? expf(l - m) : 0.f;
        float ssum = wave_reduce_sum(ex);
        float inv = 1.f / fmaxf(ssum, 1e-16f);
        int sub = lane >> 3;          // which of 8 edges in the group
        int cg  = (lane & 7) << 3;    // channel octet base
        float a0 = 0.f, a1 = 0.f, a2 = 0.f, a3 = 0.f;
        float a4 = 0.f, a5 = 0.f, a6 = 0.f, a7 = 0.f;
        int jmax = (deg + 7) >> 3;
        for (int j = 0; j < jmax; ++j) {
            int e = j * 8 + sub;
            int s = __shfl(s_reg, e, 64);       // all lanes participate
            float wgt = __shfl(ex, e, 64);
            if (e < deg) {                      // skip padded-slot loads
                const uint4 u = *reinterpret_cast<const uint4*>(
                    h + (size_t)s * CH + cg);
                a0 = fmaf(wgt, __uint_as_float(u.x << 16), a0);
                a1 = fmaf(wgt, __uint_as_float(u.x & 0xFFFF0000u), a1);
                a2 = fmaf(wgt, __uint_as_float(u.y << 16), a2);
                a3 = fmaf(wgt, __uint_as_float(u.y & 0xFFFF0000u), a3);
                a4 = fmaf(wgt, __uint_as_float(u.z << 16), a4);
                a5 = fmaf(wgt, __uint_as_float(u.z & 0xFFFF0000u), a5);
                a6 = fmaf(wgt, __uint_as_float(u.w << 16), a6);
                a7 = fmaf(wgt, __uint_as_float(u.w & 0xFFFF0000u), a7);
            }
        }
#pragma unroll
        for (int msk = 8; msk <= 32; msk <<= 1) {
            a0 += __shfl_xor(a0, msk, 64); a1 += __shfl_xor(a1, msk, 64);
            a2 += __shfl_xor(a2, msk, 64); a3 += __shfl_xor(a3, msk, 64);
            a4 += __shfl_xor(a4, msk, 64); a5 += __shfl_xor(a5, msk, 64);
            a6 += __shfl_xor(a6, msk, 64); a7 += __shfl_xor(a7, msk, 64);
        }
        if (lane < 8) {
            const float4* b4 = (const float4*)bias;
            float4 bA = b4[lane * 2], bB = b4[lane * 2 + 1];
            float4 oA, oB;
            oA.x = a0 * inv + bA.x; oA.y = a1 * inv + bA.y;
            oA.z = a2 * inv + bA.z; oA.w = a3 * inv + bA.w;
            oB.x = a4 * inv + bB.x; oB.y = a5 * inv + bB.y;
            oB.z = a6 * inv + bB.z; oB.w = a7 * inv + bB.w;
            oA.x = (oA.x > 0.f) ? oA.x : expm1f(oA.x);
            oA.y = (oA.y > 0.f) ? oA.y : expm1f(oA.y);
            oA.z = (oA.z > 0.f) ? oA.z : expm1f(oA.z);
            oA.w = (oA.w > 0.f) ? oA.w : expm1f(oA.w);
            oB.x = (oB.x > 0.f) ? oB.x : expm1f(oB.x);
            oB.y = (oB.y > 0.f) ? oB.y : expm1f(oB.y);
            oB.z = (oB.z > 0.f) ? oB.z : expm1f(oB.z);
            oB.w = (oB.w > 0.f) ? oB.w : expm1f(oB.w);
            float4* op = (float4*)(out + (size_t)n * CH + (lane << 3));
            op[0] = oA; op[1] = oB;
        }
    } else {
        // rare fallback: recompute logits, lane-per-channel
        float m = -1e30f;
        for (int i = beg + lane; i < end; i += 64) {
            float v = as[csr_src[i]] + adn;
            v = (v >= 0.f) ? v : 0.2f * v;
            m = fmaxf(m, v);
        }
        m = wave_reduce_max(m);
        float ssum = 0.f;
        for (int i = beg + lane; i < end; i += 64) {
            float v = as[csr_src[i]] + adn;
            v = (v >= 0.f) ? v : 0.2f * v;
            ssum += expf(v - m);
        }
        ssum = wave_reduce_sum(ssum);
        float inv = 1.f / fmaxf(ssum, 1e-16f);
        float acc = 0.f;
        for (int i = beg; i < end; ++i) {
            int s = csr_src[i];
            float v = as[s] + adn;
            v = (v >= 0.f) ? v : 0.2f * v;
            float ww = expf(v - m);
            acc = fmaf(ww, __bfloat162float(h[(size_t)s * CH + lane]), acc);
        }
        acc = acc * inv + bias[lane];
        out[n * CH + lane] = (acc > 0.f) ? acc : expm1f(acc);
    }
}

// ---------------- pooling (atomic-free, fused divide) ----------------

__global__ __launch_bounds__(256) void pool_kernel(
    const float* __restrict__ h, const int* __restrict__ gstart,
    float* __restrict__ out)
{
    __shared__ float red[4][64];
    int g = blockIdx.x;
    int t = threadIdx.x, w = t >> 6, lane = t & 63;
    int beg = gstart[g], end = gstart[g + 1];
    float acc = 0.f;
    for (int n = beg + w; n < end; n += 4) acc += h[n * CH + lane];
    red[w][lane] = acc;
    __syncthreads();
    if (w == 0) {
        float v = red[0][lane] + red[1][lane] + red[2][lane] + red[3][lane];
        float c = (float)(end - beg);
        out[g * CH + lane] = v / fmaxf(c, 1.f);
    }
}

// ---------------- launch ----------------

extern "C" void kernel_launch(void* const* d_in, const int* in_sizes, int n_in,
                              void* d_out, int out_size, void* d_ws, size_t ws_size,
                              hipStream_t stream)
{
    const float* x   = (const float*)d_in[0];
    const int*   ei  = (const int*)d_in[1];
    const int*   bat = (const int*)d_in[2];
    const float* W1  = (const float*)d_in[3];
    const float* as1 = (const float*)d_in[4];
    const float* ad1 = (const float*)d_in[5];
    const float* b1  = (const float*)d_in[6];
    const float* W2  = (const float*)d_in[7];
    const float* as2 = (const float*)d_in[8];
    const float* ad2 = (const float*)d_in[9];
    const float* b2  = (const float*)d_in[10];
    float* out = (float*)d_out;

    char* ws = (char*)d_ws;
    size_t off = 0;
    auto alloc = [&](size_t bytes) -> void* {
        void* p = ws + off;
        off += (bytes + 255) & ~size_t(255);
        return p;
    };
    __hip_bfloat16* hbuf = (__hip_bfloat16*)alloc(sizeof(__hip_bfloat16) * N_NODES_C * CH);
    float* obuf    = (float*)alloc(sizeof(float) * N_NODES_C * CH);
    float* alpha_s = (float*)alloc(sizeof(float) * N_NODES_C);
    float* alpha_d = (float*)alloc(sizeof(float) * N_NODES_C);
    int*   bucket_size = (int*)alloc(sizeof(int) * NBUCK);
    int*   bucket_base = (int*)alloc(sizeof(int) * (NBUCK + 1));
    int*   blk_base    = (int*)alloc(sizeof(int) * NB_BUCK * NBUCK);
    unsigned int* buck_edges = (unsigned int*)alloc(sizeof(unsigned) * E_TOT_C);
    unsigned short* csr_src = (unsigned short*)alloc(sizeof(unsigned short) * E_TOT_C);
    int*   row_ptr = (int*)alloc(sizeof(int) * (N_NODES_C + 1));
    int*   gstart  = (int*)alloc(sizeof(int) * (N_GRAPHS_C + 1));

    const int NB_AGG = N_NODES_C / 4;    // 12500 blocks, wave-per-node
    const int NB_TRF = N_NODES_C / 16;   // 3125 blocks, 16 nodes/block

    // CSR build (counting sort; writes coalesced or L2-merged)
    gstart_kernel<<<196, 256, 0, stream>>>(bat, gstart, bucket_size);
    bucket_count<<<NB_BUCK, 256, 0, stream>>>(ei, bucket_size, blk_base);
    scan_buckets<<<1, 512, 0, stream>>>(bucket_size, bucket_base);
    bucket_write<<<NB_BUCK, 256, 0, stream>>>(ei, bucket_base, blk_base, buck_edges);
    bucket_to_csr<<<NBUCK, 256, 0, stream>>>(buck_edges, bucket_base, csr_src, row_ptr);

    // layer 1
    transform_kernel<<<NB_TRF, 256, 0, stream>>>(x, W1, as1, ad1, hbuf, alpha_s, alpha_d);
    aggregate_kernel<<<NB_AGG, 256, 0, stream>>>(hbuf, alpha_s, alpha_d, b1,
                                                 row_ptr, csr_src, obuf);
    // layer 2
    transform_kernel<<<NB_TRF, 256, 0, stream>>>(obuf, W2, as2, ad2, hbuf, alpha_s, alpha_d);
    aggregate_kernel<<<NB_AGG, 256, 0, stream>>>(hbuf, alpha_s, alpha_d, b2,
                                                 row_ptr, csr_src, obuf);

    // global mean pool
    pool_kernel<<<N_GRAPHS_C, 256, 0, stream>>>(obuf, gstart, out);
}

// Round 6
// 241.193 us; speedup vs baseline: 2.5181x; 1.0145x over previous
//
#include <hip/hip_runtime.h>
#include <hip/hip_bf16.h>
#include <math.h>

#define N_NODES_C 50000
#define N_EDGES_C 800000
#define E_TOT_C   (N_EDGES_C + N_NODES_C)   // 850000 incl. self-loops
#define N_GRAPHS_C 512
#define CH 64
#define NBUCK 391        // dst >> 7 -> 391 buckets of <=128 nodes
#define NB_BUCK 160      // blocks for the bucket_build pass
#define BCAP 3328        // fixed bucket capacity (mean 2176, sigma~45: +25 sigma)

__device__ __forceinline__ float wave_reduce_sum(float v) {
#pragma unroll
    for (int m = 32; m >= 1; m >>= 1) v += __shfl_xor(v, m, 64);
    return v;
}
__device__ __forceinline__ float wave_reduce_max(float v) {
#pragma unroll
    for (int m = 32; m >= 1; m >>= 1) v = fmaxf(v, __shfl_xor(v, m, 64));
    return v;
}

// ---------------- CSR build (fixed-capacity buckets, 3 dispatches) ----------

// graph boundaries from sorted batch; also zeroes bucket_cnt
__global__ __launch_bounds__(256) void gstart_kernel(const int* __restrict__ batch,
                                                     int* __restrict__ gstart,
                                                     int* __restrict__ bucket_cnt) {
    int i = blockIdx.x * 256 + threadIdx.x;
    if (i < NBUCK) bucket_cnt[i] = 0;
    if (i >= N_NODES_C) return;
    int bcur = batch[i];
    int bprev = (i > 0) ? batch[i - 1] : -1;
    for (int g = bprev + 1; g <= bcur; ++g) gstart[g] = i;
    if (i == N_NODES_C - 1)
        for (int g = bcur + 1; g <= N_GRAPHS_C; ++g) gstart[g] = N_NODES_C;
}

// one pass: per-block LDS histogram -> global reserve -> packed write into
// fixed-capacity bucket regions (buck_edges[b*BCAP + pos] = (ldst<<16)|src)
__global__ __launch_bounds__(256) void bucket_build(const int* __restrict__ ei,
                                                    int* __restrict__ bucket_cnt,
                                                    unsigned int* __restrict__ buck_edges) {
    __shared__ int cnt[NBUCK];
    __shared__ int lbase[NBUCK];
    int t = threadIdx.x, blk = blockIdx.x;
    for (int i = t; i < NBUCK; i += 256) cnt[i] = 0;
    __syncthreads();
    const int CHUNK = (E_TOT_C + NB_BUCK - 1) / NB_BUCK;
    int beg = blk * CHUNK, end = min(beg + CHUNK, E_TOT_C);
    for (int e = beg + t; e < end; e += 256) {
        int d = (e < N_EDGES_C) ? ei[N_EDGES_C + e] : (e - N_EDGES_C);
        atomicAdd(&cnt[d >> 7], 1);
    }
    __syncthreads();
    for (int b = t; b < NBUCK; b += 256) {
        int c = cnt[b];
        lbase[b] = (c > 0) ? atomicAdd(&bucket_cnt[b], c) : 0;
        cnt[b] = 0;                       // reuse as local cursor
    }
    __syncthreads();
    for (int e = beg + t; e < end; e += 256) {
        int s_, d_;
        if (e < N_EDGES_C) { s_ = ei[e]; d_ = ei[N_EDGES_C + e]; }
        else               { s_ = d_ = e - N_EDGES_C; }
        int b = d_ >> 7;
        int pos = lbase[b] + atomicAdd(&cnt[b], 1);
        buck_edges[b * BCAP + pos] = ((unsigned)(d_ & 127) << 16) | (unsigned)s_;
    }
}

// one block per bucket: per-node CSR in LDS, coalesced write; row_ptr packed
// as (global_begin << 8) | degree  (begin < 1.31M, deg <= 255)
__global__ __launch_bounds__(256) void bucket_to_csr(const unsigned int* __restrict__ buck_edges,
                                                     const int* __restrict__ bucket_cnt,
                                                     unsigned short* __restrict__ csr_src,
                                                     unsigned int* __restrict__ row_ptr) {
    __shared__ unsigned int ebuf[BCAP];
    __shared__ unsigned short sbuf[BCAP];
    __shared__ int deg[128], sc[128], off[128], cur[128];
    int bb = blockIdx.x, t = threadIdx.x;
    int base = bb * BCAP;
    int size = min(bucket_cnt[bb], BCAP);
    int node0 = bb << 7;
    int nnodes = min(128, N_NODES_C - node0);
    for (int i = t; i < size; i += 256) ebuf[i] = buck_edges[base + i];
    if (t < 128) deg[t] = 0;
    __syncthreads();
    for (int i = t; i < size; i += 256) atomicAdd(&deg[(ebuf[i] >> 16) & 127], 1);
    __syncthreads();
    if (t < 128) sc[t] = deg[t];
    __syncthreads();
    for (int o = 1; o < 128; o <<= 1) {
        int a = (t < 128 && t >= o) ? sc[t - o] : 0;
        __syncthreads();
        if (t < 128) sc[t] += a;
        __syncthreads();
    }
    if (t < 128) { off[t] = sc[t] - deg[t]; cur[t] = 0; }
    __syncthreads();
    for (int i = t; i < size; i += 256) {
        unsigned pk = ebuf[i];
        int l = (pk >> 16) & 127;
        int p = atomicAdd(&cur[l], 1);
        sbuf[off[l] + p] = (unsigned short)(pk & 0xFFFFu);
    }
    __syncthreads();
    for (int i = t; i < size; i += 256) csr_src[base + i] = sbuf[i];
    if (t < nnodes)
        row_ptr[node0 + t] = ((unsigned)(base + off[t]) << 8) | (unsigned)min(deg[t], 255);
}

// ---------------- per-layer kernels ----------------

// h = x @ W fused with alpha dots; 16 nodes/block (4 per wave), h stored bf16
__global__ __launch_bounds__(256) void transform_kernel(
    const float* __restrict__ xin, const float* __restrict__ W,
    const float* __restrict__ a_s, const float* __restrict__ a_d,
    __hip_bfloat16* __restrict__ hout, float* __restrict__ as_out,
    float* __restrict__ ad_out)
{
    __shared__ float Wl[64][64];     // [k][c]
    __shared__ float xs[16][64];
    __shared__ float asv[64], adv[64];
    int t = threadIdx.x;
    const float4* W4 = (const float4*)W;
    float4* Wl4 = (float4*)&Wl[0][0];
    for (int i = t; i < 1024; i += 256) Wl4[i] = W4[i];
    if (t < 64) { asv[t] = a_s[t]; adv[t] = a_d[t]; }
    int n0 = blockIdx.x * 16;        // 50000 % 16 == 0
    ((float4*)&xs[0][0])[t] = ((const float4*)(xin + (size_t)n0 * CH))[t];
    __syncthreads();
    int w = t >> 6, c = t & 63;
    int r0 = w * 4;
    float a0 = 0.f, a1 = 0.f, a2 = 0.f, a3 = 0.f;
#pragma unroll
    for (int k = 0; k < 64; ++k) {
        float wl = Wl[k][c];
        a0 = fmaf(xs[r0 + 0][k], wl, a0);
        a1 = fmaf(xs[r0 + 1][k], wl, a1);
        a2 = fmaf(xs[r0 + 2][k], wl, a2);
        a3 = fmaf(xs[r0 + 3][k], wl, a3);
    }
    size_t hb = (size_t)(n0 + r0) * CH + c;
    hout[hb + 0 * CH] = __float2bfloat16(a0);
    hout[hb + 1 * CH] = __float2bfloat16(a1);
    hout[hb + 2 * CH] = __float2bfloat16(a2);
    hout[hb + 3 * CH] = __float2bfloat16(a3);
    float av = asv[c], dv = adv[c];
    float s0 = wave_reduce_sum(a0 * av), d0 = wave_reduce_sum(a0 * dv);
    float s1 = wave_reduce_sum(a1 * av), d1 = wave_reduce_sum(a1 * dv);
    float s2 = wave_reduce_sum(a2 * av), d2 = wave_reduce_sum(a2 * dv);
    float s3 = wave_reduce_sum(a3 * av), d3 = wave_reduce_sum(a3 * dv);
    if (c == 0) {
        int n = n0 + r0;
        as_out[n + 0] = s0; ad_out[n + 0] = d0;
        as_out[n + 1] = s1; ad_out[n + 1] = d1;
        as_out[n + 2] = s2; ad_out[n + 2] = d2;
        as_out[n + 3] = s3; ad_out[n + 3] = d3;
    }
}

// segment softmax + weighted aggregation + bias + ELU; wave-per-dst-node.
// row_ptr packed: beg = rp>>8, deg = rp&255.
__global__ __launch_bounds__(256) void aggregate_kernel(
    const __hip_bfloat16* __restrict__ h, const float* __restrict__ as,
    const float* __restrict__ ad, const float* __restrict__ bias,
    const unsigned int* __restrict__ row_ptr, const unsigned short* __restrict__ csr_src,
    float* __restrict__ out)
{
    int t = threadIdx.x;
    int w = t >> 6, lane = t & 63;
    int n = blockIdx.x * 4 + w;
    unsigned rp = row_ptr[n];
    int beg = (int)(rp >> 8);
    int deg = (int)(rp & 255u);      // >= 1 (self-loop)
    float adn = ad[n];
    if (deg <= 64) {
        int s_reg = (int)csr_src[beg + min(lane, deg - 1)];   // coalesced 2B
        float l = -1e30f;
        if (lane < deg) {
            float v = as[s_reg] + adn;                        // random 4B gather
            l = (v >= 0.f) ? v : 0.2f * v;
        }
        float m = wave_reduce_max(l);
        float ex = (lane < deg) ? expf(l - m) : 0.f;
        float ssum = wave_reduce_sum(ex);
        float inv = 1.f / fmaxf(ssum, 1e-16f);
        int sub = lane >> 3;          // which of 8 edges in the group
        int cg  = (lane & 7) << 3;    // channel octet base
        float a0 = 0.f, a1 = 0.f, a2 = 0.f, a3 = 0.f;
        float a4 = 0.f, a5 = 0.f, a6 = 0.f, a7 = 0.f;
        int jmax = (deg + 7) >> 3;
        for (int j = 0; j < jmax; ++j) {
            int e = j * 8 + sub;
            int s = __shfl(s_reg, e, 64);       // all lanes participate
            float wgt = __shfl(ex, e, 64);
            if (e < deg) {                      // skip padded-slot loads
                const uint4 u = *reinterpret_cast<const uint4*>(
                    h + (size_t)s * CH + cg);
                a0 = fmaf(wgt, __uint_as_float(u.x << 16), a0);
                a1 = fmaf(wgt, __uint_as_float(u.x & 0xFFFF0000u), a1);
                a2 = fmaf(wgt, __uint_as_float(u.y << 16), a2);
                a3 = fmaf(wgt, __uint_as_float(u.y & 0xFFFF0000u), a3);
                a4 = fmaf(wgt, __uint_as_float(u.z << 16), a4);
                a5 = fmaf(wgt, __uint_as_float(u.z & 0xFFFF0000u), a5);
                a6 = fmaf(wgt, __uint_as_float(u.w << 16), a6);
                a7 = fmaf(wgt, __uint_as_float(u.w & 0xFFFF0000u), a7);
            }
        }
#pragma unroll
        for (int msk = 8; msk <= 32; msk <<= 1) {
            a0 += __shfl_xor(a0, msk, 64); a1 += __shfl_xor(a1, msk, 64);
            a2 += __shfl_xor(a2, msk, 64); a3 += __shfl_xor(a3, msk, 64);
            a4 += __shfl_xor(a4, msk, 64); a5 += __shfl_xor(a5, msk, 64);
            a6 += __shfl_xor(a6, msk, 64); a7 += __shfl_xor(a7, msk, 64);
        }
        if (lane < 8) {
            const float4* b4 = (const float4*)bias;
            float4 bA = b4[lane * 2], bB = b4[lane * 2 + 1];
            float4 oA, oB;
            oA.x = a0 * inv + bA.x; oA.y = a1 * inv + bA.y;
            oA.z = a2 * inv + bA.z; oA.w = a3 * inv + bA.w;
            oB.x = a4 * inv + bB.x; oB.y = a5 * inv + bB.y;
            oB.z = a6 * inv + bB.z; oB.w = a7 * inv + bB.w;
            oA.x = (oA.x > 0.f) ? oA.x : expm1f(oA.x);
            oA.y = (oA.y > 0.f) ? oA.y : expm1f(oA.y);
            oA.z = (oA.z > 0.f) ? oA.z : expm1f(oA.z);
            oA.w = (oA.w > 0.f) ? oA.w : expm1f(oA.w);
            oB.x = (oB.x > 0.f) ? oB.x : expm1f(oB.x);
            oB.y = (oB.y > 0.f) ? oB.y : expm1f(oB.y);
            oB.z = (oB.z > 0.f) ? oB.z : expm1f(oB.z);
            oB.w = (oB.w > 0.f) ? oB.w : expm1f(oB.w);
            float4* op = (float4*)(out + (size_t)n * CH + (lane << 3));
            op[0] = oA; op[1] = oB;
        }
    } else {
        // rare fallback (64 < deg <= 255): recompute logits, lane-per-channel
        int end = beg + deg;
        float m = -1e30f;
        for (int i = beg + lane; i < end; i += 64) {
            float v = as[csr_src[i]] + adn;
            v = (v >= 0.f) ? v : 0.2f * v;
            m = fmaxf(m, v);
        }
        m = wave_reduce_max(m);
        float ssum = 0.f;
        for (int i = beg + lane; i < end; i += 64) {
            float v = as[csr_src[i]] + adn;
            v = (v >= 0.f) ? v : 0.2f * v;
            ssum += expf(v - m);
        }
        ssum = wave_reduce_sum(ssum);
        float inv = 1.f / fmaxf(ssum, 1e-16f);
        float acc = 0.f;
        for (int i = beg; i < end; ++i) {
            int s = csr_src[i];
            float v = as[s] + adn;
            v = (v >= 0.f) ? v : 0.2f * v;
            float ww = expf(v - m);
            acc = fmaf(ww, __bfloat162float(h[(size_t)s * CH + lane]), acc);
        }
        acc = acc * inv + bias[lane];
        out[n * CH + lane] = (acc > 0.f) ? acc : expm1f(acc);
    }
}

// ---------------- pooling (atomic-free, fused divide) ----------------

__global__ __launch_bounds__(256) void pool_kernel(
    const float* __restrict__ h, const int* __restrict__ gstart,
    float* __restrict__ out)
{
    __shared__ float red[4][64];
    int g = blockIdx.x;
    int t = threadIdx.x, w = t >> 6, lane = t & 63;
    int beg = gstart[g], end = gstart[g + 1];
    float acc = 0.f;
    for (int n = beg + w; n < end; n += 4) acc += h[n * CH + lane];
    red[w][lane] = acc;
    __syncthreads();
    if (w == 0) {
        float v = red[0][lane] + red[1][lane] + red[2][lane] + red[3][lane];
        float c = (float)(end - beg);
        out[g * CH + lane] = v / fmaxf(c, 1.f);
    }
}

// ---------------- launch ----------------

extern "C" void kernel_launch(void* const* d_in, const int* in_sizes, int n_in,
                              void* d_out, int out_size, void* d_ws, size_t ws_size,
                              hipStream_t stream)
{
    const float* x   = (const float*)d_in[0];
    const int*   ei  = (const int*)d_in[1];
    const int*   bat = (const int*)d_in[2];
    const float* W1  = (const float*)d_in[3];
    const float* as1 = (const float*)d_in[4];
    const float* ad1 = (const float*)d_in[5];
    const float* b1  = (const float*)d_in[6];
    const float* W2  = (const float*)d_in[7];
    const float* as2 = (const float*)d_in[8];
    const float* ad2 = (const float*)d_in[9];
    const float* b2  = (const float*)d_in[10];
    float* out = (float*)d_out;

    char* ws = (char*)d_ws;
    size_t off = 0;
    auto alloc = [&](size_t bytes) -> void* {
        void* p = ws + off;
        off += (bytes + 255) & ~size_t(255);
        return p;
    };
    __hip_bfloat16* hbuf = (__hip_bfloat16*)alloc(sizeof(__hip_bfloat16) * N_NODES_C * CH);
    float* obuf    = (float*)alloc(sizeof(float) * N_NODES_C * CH);
    float* alpha_s = (float*)alloc(sizeof(float) * N_NODES_C);
    float* alpha_d = (float*)alloc(sizeof(float) * N_NODES_C);
    int*   bucket_cnt = (int*)alloc(sizeof(int) * NBUCK);
    unsigned int* buck_edges = (unsigned int*)alloc(sizeof(unsigned) * NBUCK * BCAP);
    unsigned short* csr_src  = (unsigned short*)alloc(sizeof(unsigned short) * NBUCK * BCAP);
    unsigned int* row_ptr    = (unsigned int*)alloc(sizeof(unsigned) * N_NODES_C);
    int*   gstart  = (int*)alloc(sizeof(int) * (N_GRAPHS_C + 1));

    const int NB_AGG = N_NODES_C / 4;    // 12500 blocks, wave-per-node
    const int NB_TRF = N_NODES_C / 16;   // 3125 blocks, 16 nodes/block

    // CSR build: 3 dispatches (fixed-capacity buckets, no global scan)
    gstart_kernel<<<196, 256, 0, stream>>>(bat, gstart, bucket_cnt);
    bucket_build<<<NB_BUCK, 256, 0, stream>>>(ei, bucket_cnt, buck_edges);
    bucket_to_csr<<<NBUCK, 256, 0, stream>>>(buck_edges, bucket_cnt, csr_src, row_ptr);

    // layer 1
    transform_kernel<<<NB_TRF, 256, 0, stream>>>(x, W1, as1, ad1, hbuf, alpha_s, alpha_d);
    aggregate_kernel<<<NB_AGG, 256, 0, stream>>>(hbuf, alpha_s, alpha_d, b1,
                                                 row_ptr, csr_src, obuf);
    // layer 2
    transform_kernel<<<NB_TRF, 256, 0, stream>>>(obuf, W2, as2, ad2, hbuf, alpha_s, alpha_d);
    aggregate_kernel<<<NB_AGG, 256, 0, stream>>>(hbuf, alpha_s, alpha_d, b2,
                                                 row_ptr, csr_src, obuf);

    // global mean pool
    pool_kernel<<<N_GRAPHS_C, 256, 0, stream>>>(obuf, gstart, out);
}